// Round 3
// baseline (116.486 us; speedup 1.0000x reference)
//
#include <hip/hip_runtime.h>
#include <hip/hip_bf16.h>
#include <math.h>

// MMD (InfoVAE RBF kernel), N=8192, D=128, fp32 in, scalar fp32 out.
//
// Round 13: 256x256 tiles (2x staging reuse) + conflict-free 64B-row swizzle.
//   r12 post-mortem:
//   (a) 4-chunk swizzle csw=quad^(lr&3) had 2-way phase conflicts (4.2M
//       SQ_LDS_BANK_CONFLICT): bank-group bits are {row&1, chunk}; lanes
//       0-7 hit only 4/8 groups. Fix: s(r)=(r>>1)&3 -> phase lanes map
//       (lr&1,(lr>>1)&3) bijectively onto 8 groups. Staging source chunk
//       gch=(lane&3)^((lane>>3)&3) (l-invariant), read csw=quad^((lr>>1)&3).
//   (b) Counted vmcnt didn't lift MfmaUtil: r10/r12 are STAGING-bound.
//       Known-good global_load_lds kernels (m97/m201/HK) all sustain
//       ~20-23 B/cy/CU on the DMA path; our 2 MB/CU staged -> >=39 us
//       floor at 64 FLOP/staged-byte. Fix: 256x256 tile = 128 FLOP/byte,
//       2080 blocks x 128 KB = 266 MB total -> ~20 us staging floor,
//       matching the 16.7 us MFMA floor.
//   Structure: 512 thr / 8 waves (2x4 grid, 128x64 per wave, acc 8x4),
//   r12's proven 4-slice dbuf sync template (vmcnt(4) counted waits,
//   fused {wait;barrier} asm, sched_barrier before MFMA clusters).
//   LDS 64 KB dbuf (2 x (A 16K + B 16K)), ~200 VGPR, 1 block/CU.
//   Numerics: per-element MFMA K-chain identical to r10/r12 (4x
//   16x16x32 ascending K); epilogue identical; fp32 partials now 32
//   terms (<=32); fp64 block/global accumulation; X/Y boundary at
//   tile 32. absmax expected 5.96e-8 (threshold 7.15e-8).

#define NN 8192
#define DD 128
#define TZ 16384
#define TILES 64                            // 256-row tiles
#define NBLOCKS (TILES * (TILES + 1) / 2)   // 2080

typedef __attribute__((ext_vector_type(8))) short bf16x8;
typedef __attribute__((ext_vector_type(4))) float f32x4;
typedef __attribute__((ext_vector_type(2))) float f32x2;

#if __has_builtin(__builtin_amdgcn_exp2f)
#define EXP2F __builtin_amdgcn_exp2f
#else
#define EXP2F exp2f
#endif

constexpr float LOG2E = 0x1.715476p+0f;
constexpr float S2 = LOG2E / 8192.0f;              // 2*log2e/16384

// ---- ws layout ----
constexpr size_t WS_NORM = 2048;                   // sums: 256 fp64 slots
constexpr size_t WS_Z    = WS_NORM + (size_t)TZ * sizeof(float);

__device__ __forceinline__ void gload_lds16(const void* g, void* l) {
  __builtin_amdgcn_global_load_lds(
      (const __attribute__((address_space(1))) void*)g,
      (__attribute__((address_space(3))) void*)l, 16, 0, 0);
}

__global__ __launch_bounds__(256) void prep(
    const float* __restrict__ X, const float* __restrict__ Y,
    __hip_bfloat16* __restrict__ Z, float* __restrict__ normZ,
    double* __restrict__ sums) {
  if (blockIdx.x == 0) sums[threadIdx.x] = 0.0;    // 256 slots

  const int row = blockIdx.x * 4 + (threadIdx.x >> 6);
  const int lane = threadIdx.x & 63;
  const float* __restrict__ src =
      (row < NN) ? (X + (size_t)row * DD) : (Y + (size_t)(row - NN) * DD);
  const float2 v = *reinterpret_cast<const float2*>(src + 2 * lane);

  float n = v.x * v.x + v.y * v.y;
  *reinterpret_cast<__hip_bfloat162*>(Z + (size_t)row * DD + 2 * lane) =
      __hip_bfloat162{__float2bfloat16(v.x), __float2bfloat16(v.y)};

#pragma unroll
  for (int o = 32; o > 0; o >>= 1) n += __shfl_down(n, o);
  if (lane == 0) normZ[row] = n * (-LOG2E / 16384.0f);  // pre-scaled
}

__device__ __forceinline__ int tri_start(int i) {
  return i * TILES - (i * (i - 1)) / 2;
}

__global__ __launch_bounds__(512, 2) void mmd_mfma(
    const __hip_bfloat16* __restrict__ Z, const float* __restrict__ normZ,
    double* __restrict__ sums) {
  // 2 bufs x (A 16 KB @ +0, B 16 KB @ +16384) = 64 KB (+pad).
  __shared__ alignas(16) char lds[2 * 32768 + 256];

  const int t = blockIdx.x;
  int I = (int)((129.0 - sqrt(129.0 * 129.0 - 8.0 * (double)t)) * 0.5);
  if (I > 63) I = 63;
  if (I < 0) I = 0;
  while (I < 63 && tri_start(I + 1) <= t) ++I;
  while (I > 0 && tri_start(I) > t) --I;
  const int J = I + (t - tri_start(I));

  const int tid = threadIdx.x;
  const int lane = tid & 63, wave = tid >> 6;      // 8 waves
  const int wr = wave >> 2, wc = wave & 3;         // 2x4 grid: 128x64/wave
  const int lr = lane & 15, quad = lane >> 4;      // MFMA lane decomposition

  // ---- staging geometry ----
  // Issue (wave w, half l in {0,1}) for a panel: LDS dst = panel +
  // w*2048 + l*1024 (wave-uniform); DMA lane-maps +lane*16 -> panel row
  // r = 32w + 16l + (lane>>2), chunk c' = lane&3. Stored global chunk
  // must be c' ^ s(r), s(r) = (r>>1)&3. s is l-invariant and equals
  // (lane>>3)&3 here (32w>>1 = 16w == 0 mod 4; 16l>>1 = 8l == 0 mod 4).
  const char* Zb = (const char*)Z;
  const int rd0 = (wave << 5) + (lane >> 2);           // l=0 panel row
  const int gch = (lane & 3) ^ ((lane >> 3) & 3);
  const char* srcA = Zb + ((size_t)(I * 256 + rd0)) * 256 + gch * 16;
  const char* srcB = Zb + ((size_t)(J * 256 + rd0)) * 256 + gch * 16;
  char* ldw = lds + wave * 2048;                       // wave-uniform

#define STAGE(s, buf) do {                                               \
    gload_lds16(srcA + (s) * 64,        ldw + (buf) * 32768);            \
    gload_lds16(srcA + (s) * 64 + 4096, ldw + (buf) * 32768 + 1024);     \
    gload_lds16(srcB + (s) * 64,        ldw + (buf) * 32768 + 16384);    \
    gload_lds16(srcB + (s) * 64 + 4096, ldw + (buf) * 32768 + 17408);    \
  } while (0)

  // ---- fragment read bases ----
  // Read row r, global chunk quad: LDS chunk = quad ^ s(r); for A rows
  // r = wr*128 + i*16 + lr, s(r) = (lr>>1)&3 (i*16>>1 = 8i == 0 mod 4).
  // Phase-conflict-free: lanes 8k..8k+7 map (lr&1,(lr>>1)&3) onto all 8
  // 16B bank-groups {row&1, chunk}.
  const int csw = (quad ^ ((lr >> 1) & 3)) << 4;
  const char* aRd = lds + (wr * 128 + lr) * 64 + csw;
  const char* bRd = lds + 16384 + (wc * 64 + lr) * 64 + csw;

  bf16x8 a[8], b[4];
  f32x4 acc[8][4] = {};

#define LOADFRAGS(buf) do {                                              \
    _Pragma("unroll")                                                    \
    for (int i = 0; i < 8; ++i)                                          \
      a[i] = *reinterpret_cast<const bf16x8*>(aRd + (buf) * 32768 + i * 1024); \
    _Pragma("unroll")                                                    \
    for (int j = 0; j < 4; ++j)                                          \
      b[j] = *reinterpret_cast<const bf16x8*>(bRd + (buf) * 32768 + j * 1024); \
  } while (0)

#define MFMAS() do {                                                     \
    _Pragma("unroll")                                                    \
    for (int i = 0; i < 8; ++i)                                          \
      _Pragma("unroll")                                                  \
      for (int j = 0; j < 4; ++j)                                        \
        acc[i][j] = __builtin_amdgcn_mfma_f32_16x16x32_bf16(             \
            a[i], b[j], acc[i][j], 0, 0, 0);                             \
  } while (0)

  // Prologue: 8 DMA issues in flight per wave (slices 0,1).
  STAGE(0, 0);
  STAGE(1, 1);

  // ---- slice 0 (buf0) ----
  asm volatile("s_waitcnt vmcnt(4)\n\ts_barrier" ::: "memory");
  LOADFRAGS(0);
  asm volatile("s_waitcnt lgkmcnt(0)\n\ts_barrier" ::: "memory");
  __builtin_amdgcn_sched_barrier(0);
  STAGE(2, 0);                       // safe: all waves done reading buf0
  __builtin_amdgcn_sched_barrier(0);
  MFMAS();

  // ---- slice 1 (buf1) ----
  asm volatile("s_waitcnt vmcnt(4)\n\ts_barrier" ::: "memory");
  LOADFRAGS(1);
  asm volatile("s_waitcnt lgkmcnt(0)\n\ts_barrier" ::: "memory");
  __builtin_amdgcn_sched_barrier(0);
  STAGE(3, 1);
  __builtin_amdgcn_sched_barrier(0);
  MFMAS();

  // ---- slice 2 (buf0, no restage) ----
  asm volatile("s_waitcnt vmcnt(4)\n\ts_barrier" ::: "memory");
  LOADFRAGS(0);
  asm volatile("s_waitcnt lgkmcnt(0)" ::: "memory");
  __builtin_amdgcn_sched_barrier(0);
  MFMAS();

  // ---- slice 3 (buf1, no restage) ----
  asm volatile("s_waitcnt vmcnt(0)\n\ts_barrier" ::: "memory");
  LOADFRAGS(1);
  asm volatile("s_waitcnt lgkmcnt(0)" ::: "memory");
  __builtin_amdgcn_sched_barrier(0);
  MFMAS();

#undef STAGE
#undef LOADFRAGS
#undef MFMAS

  // Norms (L2-hot, loaded after the MFMA pipeline).
  const float* nzA = normZ + I * 256 + wr * 128;
  const float* nzB = normZ + J * 256 + wc * 64;
  f32x4 ar[8];
  float cb[4];
#pragma unroll
  for (int i = 0; i < 8; ++i)
    ar[i] = *reinterpret_cast<const f32x4*>(nzA + i * 16 + quad * 4);
#pragma unroll
  for (int j = 0; j < 4; ++j) cb[j] = nzB[j * 16 + lr];

  // Epilogue (C/D: col=lane&15, row=quad*4+reg), packed fp32 pairs:
  // k = exp2(acc*S2 + ra + rb), ra/rb pre-scaled by -log2e/16384.
  const f32x2 s2v = {S2, S2};
  f32x2 part01 = {0.f, 0.f}, part23 = {0.f, 0.f};
#pragma unroll
  for (int i = 0; i < 8; ++i) {
    const f32x2 ar01 = {ar[i].x, ar[i].y};
    const f32x2 ar23 = {ar[i].z, ar[i].w};
#pragma unroll
    for (int j = 0; j < 4; ++j) {
      const f32x2 rb2 = {cb[j], cb[j]};
      const f32x2 base01 = ar01 + rb2;
      const f32x2 base23 = ar23 + rb2;
      const f32x2 acc01 = {acc[i][j][0], acc[i][j][1]};
      const f32x2 acc23 = {acc[i][j][2], acc[i][j][3]};
      const f32x2 arg01 = __builtin_elementwise_fma(acc01, s2v, base01);
      const f32x2 arg23 = __builtin_elementwise_fma(acc23, s2v, base23);
      part01 += (f32x2){EXP2F(arg01.x), EXP2F(arg01.y)};
      part23 += (f32x2){EXP2F(arg23.x), EXP2F(arg23.y)};
    }
  }
  const f32x2 ps = part01 + part23;
  double local = (double)(ps.x + ps.y);
  double w = ((I < 32) == (J < 32)) ? 1.0 : -1.0;  // X/Y boundary: tile 32
  if (I != J) w += w;
  local *= w;

#pragma unroll
  for (int o = 32; o > 0; o >>= 1) local += __shfl_down(local, o);
  if (lane == 0)
    atomicAdd(&sums[((t & 31) << 3) | wave], local);
}

__global__ void finish(const double* __restrict__ s, float* __restrict__ out) {
  double v = s[threadIdx.x] + s[threadIdx.x + 64] + s[threadIdx.x + 128] +
             s[threadIdx.x + 192];
#pragma unroll
  for (int o = 32; o > 0; o >>= 1) v += __shfl_down(v, o);
  if (threadIdx.x == 0)
    out[0] = (float)(v * (1.0 / ((double)NN * (double)NN)));
}

extern "C" void kernel_launch(void* const* d_in, const int* in_sizes, int n_in,
                              void* d_out, int out_size, void* d_ws, size_t ws_size,
                              hipStream_t stream) {
  const float* y_inputs = (const float*)d_in[0];  // "inputs"
  const float* x_true   = (const float*)d_in[1];  // "true_samples"
  float* out = (float*)d_out;

  char* ws = (char*)d_ws;
  double* sums = (double*)ws;                     // 256 fp64 partial slots
  float* normZ = (float*)(ws + WS_NORM);
  __hip_bfloat16* Z = (__hip_bfloat16*)(ws + WS_Z);

  prep<<<TZ / 4, 256, 0, stream>>>(x_true, y_inputs, Z, normZ, sums);
  mmd_mfma<<<NBLOCKS, 512, 0, stream>>>(Z, normZ, sums);
  finish<<<1, 64, 0, stream>>>(sums, out);
}